// Round 2
// baseline (323.176 us; speedup 1.0000x reference)
//
#include <hip/hip_runtime.h>
#include <hip/hip_bf16.h>

// z_e (32,64,64,64) f32, codebook (512,64) f32.
// N = 131072 pixels, C = 64, K = 512.
// d_out (f32): [0..8388607] z_q (B,C,H,W); [8388608] loss; [8388609..] indices as float.
#define NPIX 131072
#define CDIM 64
#define KCODES 512
#define ZQ_SIZE 8388608
#define LOSS_OFF 8388608
#define IDXOUT_OFF 8388609
#define CH_STRIDE 4096      // H*W
#define B_STRIDE 262144     // C*H*W

// ws: [0] double loss_acc; [64] float c2[512]; [4096] int idx[NPIX]

// ||c_k||^2 replicating np.sum pairwise (8-accumulator) order, squares rounded first.
__global__ void k0_c2(const float* __restrict__ cb, float* __restrict__ c2) {
#pragma clang fp contract(off)
    int k = threadIdx.x + blockIdx.x * blockDim.x;
    if (k >= KCODES) return;
    const float* cr = cb + k * CDIM;
    float r[8];
    #pragma unroll
    for (int j = 0; j < 8; ++j) r[j] = cr[j] * cr[j];
    #pragma unroll
    for (int t = 1; t < 8; ++t)
        #pragma unroll
        for (int j = 0; j < 8; ++j) r[j] += cr[8 * t + j] * cr[8 * t + j];
    c2[k] = ((r[0] + r[1]) + (r[2] + r[3])) + ((r[4] + r[5]) + (r[6] + r[7]));
}

// Per pixel: replicate f32 distances d_k = (||z||^2 - 2*(z.c_k)) + ||c_k||^2,
// argmin with strict < (first index wins), matching the numpy reference.
__global__ __launch_bounds__(256) void k1_main(const float* __restrict__ z_e,
                                               const float* __restrict__ cb,
                                               const float* __restrict__ c2,
                                               int* __restrict__ idx,
                                               float* __restrict__ out) {
#pragma clang fp contract(off)
    int p = blockIdx.x * blockDim.x + threadIdx.x;
    int b = p >> 12;
    int hw = p & 4095;
    const float* zb = z_e + (size_t)b * B_STRIDE + hw;

    float z[CDIM];
    #pragma unroll
    for (int i = 0; i < CDIM; ++i) z[i] = zb[(size_t)i * CH_STRIDE];

    // ||z||^2 in np pairwise-8 order (squares rounded individually; contract off)
    float r[8];
    #pragma unroll
    for (int j = 0; j < 8; ++j) r[j] = z[j] * z[j];
    #pragma unroll
    for (int t = 1; t < 8; ++t)
        #pragma unroll
        for (int j = 0; j < 8; ++j) r[j] += z[8 * t + j] * z[8 * t + j];
    float A = ((r[0] + r[1]) + (r[2] + r[3])) + ((r[4] + r[5]) + (r[6] + r[7]));

    float m1 = 3.4e38f;
    int i1 = 0;
    for (int k = 0; k < KCODES; k += 4) {
        const float* c0 = cb + (size_t)(k + 0) * CDIM;
        const float* c1 = cb + (size_t)(k + 1) * CDIM;
        const float* c2r = cb + (size_t)(k + 2) * CDIM;
        const float* c3 = cb + (size_t)(k + 3) * CDIM;
        // sequential ascending-i FMA chain per code (BLAS sgemm microkernel order)
        float a0 = 0.f, a1 = 0.f, a2 = 0.f, a3 = 0.f;
        #pragma unroll
        for (int i = 0; i < CDIM; ++i) {
            a0 = fmaf(z[i], c0[i], a0);
            a1 = fmaf(z[i], c1[i], a1);
            a2 = fmaf(z[i], c2r[i], a2);
            a3 = fmaf(z[i], c3[i], a3);
        }
        // d = (A - 2*dot) + c2[k] : two f32 roundings, as numpy elementwise
        float d0 = (A - 2.0f * a0) + c2[k + 0];
        float d1 = (A - 2.0f * a1) + c2[k + 1];
        float d2 = (A - 2.0f * a2) + c2[k + 2];
        float d3 = (A - 2.0f * a3) + c2[k + 3];
        if (d0 < m1) { m1 = d0; i1 = k + 0; }
        if (d1 < m1) { m1 = d1; i1 = k + 1; }
        if (d2 < m1) { m1 = d2; i1 = k + 2; }
        if (d3 < m1) { m1 = d3; i1 = k + 3; }
    }
    idx[p] = i1;
    out[IDXOUT_OFF + p] = (float)i1;
}

__global__ __launch_bounds__(256) void k3_out(const float* __restrict__ z_e,
                                              const float* __restrict__ cb,
                                              const int* __restrict__ idx,
                                              float* __restrict__ out,
                                              double* __restrict__ loss_acc) {
    int p = blockIdx.x * blockDim.x + threadIdx.x;
    int b = p >> 12;
    int hw = p & 4095;
    const float* zb = z_e + (size_t)b * B_STRIDE + hw;
    float* ob = out + (size_t)b * B_STRIDE + hw;
    int k = idx[p];
    const float* cr = cb + (size_t)k * CDIM;

    float ls = 0.f;
    #pragma unroll
    for (int i = 0; i < CDIM; ++i) {
        float zq = cr[i];
        float zi = zb[(size_t)i * CH_STRIDE];
        ob[(size_t)i * CH_STRIDE] = zq;
        float d = zq - zi;
        ls = fmaf(d, d, ls);
    }

    double dls = (double)ls;
    for (int off = 32; off; off >>= 1) dls += __shfl_down(dls, off);
    __shared__ double wsum[4];
    int lane = threadIdx.x & 63, wv = threadIdx.x >> 6;
    if (lane == 0) wsum[wv] = dls;
    __syncthreads();
    if (threadIdx.x == 0) {
        double t = (wsum[0] + wsum[1]) + (wsum[2] + wsum[3]);
        atomicAdd(loss_acc, t);
    }
}

__global__ void k4_loss(float* __restrict__ out, const double* __restrict__ loss_acc) {
    out[LOSS_OFF] = (float)(1.25 * (*loss_acc) / (double)ZQ_SIZE);
}

extern "C" void kernel_launch(void* const* d_in, const int* in_sizes, int n_in,
                              void* d_out, int out_size, void* d_ws, size_t ws_size,
                              hipStream_t stream) {
    const float* z_e = (const float*)d_in[0];
    const float* cb  = (const float*)d_in[1];
    float* out = (float*)d_out;

    char* ws = (char*)d_ws;
    double* loss_acc = (double*)(ws + 0);
    float* c2 = (float*)(ws + 64);
    int* idx = (int*)(ws + 4096);

    hipMemsetAsync(d_ws, 0, 64, stream);
    k0_c2<<<2, 256, 0, stream>>>(cb, c2);
    k1_main<<<NPIX / 256, 256, 0, stream>>>(z_e, cb, c2, idx, out);
    k3_out<<<NPIX / 256, 256, 0, stream>>>(z_e, cb, idx, out, loss_acc);
    k4_loss<<<1, 1, 0, stream>>>(out, loss_acc);
}